// Round 18
// baseline (317.160 us; speedup 1.0000x reference)
//
#include <hip/hip_runtime.h>

#define SEQ 512
#define BATCH 128
#define DIM 1024
#define T 32

typedef int v2i_ __attribute__((ext_vector_type(2)));

__device__ __forceinline__ float rlf(float x, int n) {
    return __int_as_float(__builtin_amdgcn_readlane(__float_as_int(x), n));
}

// DPP row rotate right: dst[r] = src[(r-M)&15] within each 16-lane row
#define ROT(x, M) __int_as_float(__builtin_amdgcn_update_dpp( \
    __float_as_int(x), __float_as_int(x), 0x120 + (M), 0xF, 0xF, false))

// combine 16-lane row pairs (lanes l <-> l^16): pair-set {own, cross}
__device__ __forceinline__ float pairsum16(float x) {
    v2i_ r = __builtin_amdgcn_permlane16_swap(__float_as_int(x), __float_as_int(x), false, false);
    return __int_as_float(r.x) + __int_as_float(r.y);
}
__device__ __forceinline__ float pairmax16(float x) {
    v2i_ r = __builtin_amdgcn_permlane16_swap(__float_as_int(x), __float_as_int(x), false, false);
    return fmaxf(__int_as_float(r.x), __int_as_float(r.y));
}
// cross-half (lane^32) value, robust to result-pair ordering (pair-set verified r16)
__device__ __forceinline__ float cross32(float x) {
    v2i_ r = __builtin_amdgcn_permlane32_swap(__float_as_int(x), __float_as_int(x), false, false);
    int xi = __float_as_int(x);
    int sw = (r.x == xi) ? r.y : r.x;
    return __int_as_float(sw);
}

// wave-uniform mask bit: 512 bits in 8 u64 (SGPR-resident)
__device__ __forceinline__ int mbit(unsigned long long m0, unsigned long long m1,
        unsigned long long m2, unsigned long long m3, unsigned long long m4,
        unsigned long long m5, unsigned long long m6, unsigned long long m7, int i) {
    int w = i >> 6;
    unsigned long long cm =
        (w < 4) ? ((w < 2) ? (w == 0 ? m0 : m1) : (w == 2 ? m2 : m3))
                : ((w < 6) ? (w == 4 ? m4 : m5) : (w == 6 ? m6 : m7));
    return (int)((cm >> (i & 63)) & 1ULL);
}

#define BALLOTS(pre, bb) \
    unsigned long long pre##0 = __ballot(mask[(0 * 64 + tid) * BATCH + (bb)] != 0); \
    unsigned long long pre##1 = __ballot(mask[(1 * 64 + tid) * BATCH + (bb)] != 0); \
    unsigned long long pre##2 = __ballot(mask[(2 * 64 + tid) * BATCH + (bb)] != 0); \
    unsigned long long pre##3 = __ballot(mask[(3 * 64 + tid) * BATCH + (bb)] != 0); \
    unsigned long long pre##4 = __ballot(mask[(4 * 64 + tid) * BATCH + (bb)] != 0); \
    unsigned long long pre##5 = __ballot(mask[(5 * 64 + tid) * BATCH + (bb)] != 0); \
    unsigned long long pre##6 = __ballot(mask[(6 * 64 + tid) * BATCH + (bb)] != 0); \
    unsigned long long pre##7 = __ballot(mask[(7 * 64 + tid) * BATCH + (bb)] != 0);

#define MB(pre, i) mbit(pre##0, pre##1, pre##2, pre##3, pre##4, pre##5, pre##6, pre##7, (i))

// sum over the 32 distinct states in quad layout: lanes 0..15 (g0) + 32..47 (g2)
#define RLSUMQ(dst, src) { \
    float s0 = 0.f, s1 = 0.f, s2 = 0.f, s3 = 0.f; \
    _Pragma("unroll") \
    for (int n = 0; n < 8; ++n) { \
        s0 += rlf(src, n); \
        s1 += rlf(src, 8 + n); \
        s2 += rlf(src, 32 + n); \
        s3 += rlf(src, 40 + n); \
    } \
    dst = (s0 + s1) + (s2 + s3); }

// register-only half-matvec: 15 DPP rotations + 16 fma, combine row pairs
#define DPPMV(dst, pv, Eh) { \
    float q0 = (pv) * Eh[0]; \
    float q1 = ROT(pv, 1) * Eh[1]; \
    float q2 = ROT(pv, 2) * Eh[2]; \
    float q3 = ROT(pv, 3) * Eh[3]; \
    q0 = fmaf(ROT(pv, 4), Eh[4], q0); \
    q1 = fmaf(ROT(pv, 5), Eh[5], q1); \
    q2 = fmaf(ROT(pv, 6), Eh[6], q2); \
    q3 = fmaf(ROT(pv, 7), Eh[7], q3); \
    q0 = fmaf(ROT(pv, 8), Eh[8], q0); \
    q1 = fmaf(ROT(pv, 9), Eh[9], q1); \
    q2 = fmaf(ROT(pv, 10), Eh[10], q2); \
    q3 = fmaf(ROT(pv, 11), Eh[11], q3); \
    q0 = fmaf(ROT(pv, 12), Eh[12], q0); \
    q1 = fmaf(ROT(pv, 13), Eh[13], q1); \
    q2 = fmaf(ROT(pv, 14), Eh[14], q2); \
    q3 = fmaf(ROT(pv, 15), Eh[15], q3); \
    float qh_ = (q0 + q1) + (q2 + q3); \
    dst = pairsum16(qh_); }

// register-only half-maxplus (max exact under any association)
#define DPPMAX(dst, sv, Vh) { \
    float a0 = (sv) + Vh[0]; \
    float a1 = ROT(sv, 1) + Vh[1]; \
    float a2 = ROT(sv, 2) + Vh[2]; \
    float a3 = ROT(sv, 3) + Vh[3]; \
    a0 = fmaxf(a0, ROT(sv, 4) + Vh[4]); \
    a1 = fmaxf(a1, ROT(sv, 5) + Vh[5]); \
    a2 = fmaxf(a2, ROT(sv, 6) + Vh[6]); \
    a3 = fmaxf(a3, ROT(sv, 7) + Vh[7]); \
    a0 = fmaxf(a0, ROT(sv, 8) + Vh[8]); \
    a1 = fmaxf(a1, ROT(sv, 9) + Vh[9]); \
    a2 = fmaxf(a2, ROT(sv, 10) + Vh[10]); \
    a3 = fmaxf(a3, ROT(sv, 11) + Vh[11]); \
    a0 = fmaxf(a0, ROT(sv, 12) + Vh[12]); \
    a1 = fmaxf(a1, ROT(sv, 13) + Vh[13]); \
    a2 = fmaxf(a2, ROT(sv, 14) + Vh[14]); \
    a3 = fmaxf(a3, ROT(sv, 15) + Vh[15]); \
    float mh_ = fmaxf(fmaxf(a0, a1), fmaxf(a2, a3)); \
    dst = pairmax16(mh_); }

// alpha/beta: stage 128 e-rows with exp applied
#define STAGEXP(blk) do { \
    _Pragma("unroll") \
    for (int ps = 0; ps < 16; ++ps) { \
        int r = ps * 8 + r8; \
        float4 v = *(const float4*)&e[(size_t)(((blk) * 128 + r) * BATCH + b) * T + q * 4]; \
        v.x = __expf(v.x); v.y = __expf(v.y); v.z = __expf(v.z); v.w = __expf(v.w); \
        *(float4*)&ebuf[(blk) & 1][r * 32 + q * 4] = v; \
    } } while (0)

#define FLUSHPC(dstP, dstC, blk) do { \
    _Pragma("unroll") \
    for (int ps = 0; ps < 16; ++ps) { \
        int r = ps * 8 + r8; \
        float4 v = *(const float4*)&pbuf[(blk) & 1][r * 32 + q * 4]; \
        *(float4*)&dstP[(size_t)(((blk) * 128 + r) * BATCH + b) * T + q * 4] = v; \
    } \
    _Pragma("unroll") \
    for (int ps = 0; ps < 2; ++ps) { \
        int r = ps * 64 + tid; \
        dstC[(size_t)((blk) * 128 + r) * BATCH + b] = cbuf[(blk) & 1][r]; \
    } } while (0)

// viterbi: stage 64 raw e-rows (single buffer)
#define STAGEV(blk) do { \
    _Pragma("unroll") \
    for (int ps = 0; ps < 8; ++ps) { \
        int r = ps * 8 + r8; \
        float4 v = *(const float4*)&e[(size_t)(((blk) * 64 + r) * BATCH + b2) * T + q * 4]; \
        *(float4*)&ebufv[r * 32 + q * 4] = v; \
    } } while (0)

// ---------------- W transpose ----------------
__global__ void k_wt(const float* __restrict__ W, float* __restrict__ Wt)
{
    int idx = blockIdx.x * 256 + threadIdx.x;
    if (idx >= DIM * T) return;
    int d = idx >> 5, t = idx & 31;
    Wt[idx] = W[t * DIM + d];
}

// ---------------- emissions (unchanged, verified) ----------------
__global__ __launch_bounds__(256) void k_emis(const float* __restrict__ A,
        const float* __restrict__ Wt, const float* __restrict__ bias,
        float* __restrict__ e)
{
    __shared__ float lds[64 * 37];
    int tid = threadIdx.x;
    int row0 = blockIdx.x * 64;
    int row = tid & 63;
    int grp = __builtin_amdgcn_readfirstlane(tid >> 6);
    int q = tid & 7;
    int rb = tid >> 3;

    float acc[8];
    #pragma unroll
    for (int t = 0; t < 8; ++t) acc[t] = bias[grp * 8 + t];

    const float* A0 = &A[(size_t)(row0 + rb) * DIM];
    const float* A1 = &A[(size_t)(row0 + rb + 32) * DIM];

    float4 v0 = *(const float4*)&A0[q * 4];
    float4 v1 = *(const float4*)&A1[q * 4];

    for (int ck = 0; ck < 32; ++ck) {
        lds[rb * 37 + q * 4 + 0] = v0.x;
        lds[rb * 37 + q * 4 + 1] = v0.y;
        lds[rb * 37 + q * 4 + 2] = v0.z;
        lds[rb * 37 + q * 4 + 3] = v0.w;
        lds[(rb + 32) * 37 + q * 4 + 0] = v1.x;
        lds[(rb + 32) * 37 + q * 4 + 1] = v1.y;
        lds[(rb + 32) * 37 + q * 4 + 2] = v1.z;
        lds[(rb + 32) * 37 + q * 4 + 3] = v1.w;
        __syncthreads();
        if (ck < 31) {
            v0 = *(const float4*)&A0[(ck + 1) * 32 + q * 4];
            v1 = *(const float4*)&A1[(ck + 1) * 32 + q * 4];
        }
        #pragma unroll
        for (int d = 0; d < 32; ++d) {
            float av = lds[row * 37 + d];
            const float* wrow = &Wt[(ck * 32 + d) * T + grp * 8];
            #pragma unroll
            for (int t = 0; t < 8; ++t)
                acc[t] = fmaf(av, wrow[t], acc[t]);
        }
        __syncthreads();
    }

    float4* eo = (float4*)&e[(size_t)(row0 + row) * T + grp * 8];
    float4 o0, o1;
    o0.x = acc[0]; o0.y = acc[1]; o0.z = acc[2]; o0.w = acc[3];
    o1.x = acc[4]; o1.y = acc[5]; o1.z = acc[6]; o1.w = acc[7];
    eo[0] = o0; eo[1] = o1;
}

// ---------------- recursions ----------------
// Quad-layout DPP matvec, CORRECTED ror direction: ROT(x,m)=src[(r-m)&15],
// so tables index source sigma(m) = s0h + ((rr - m) & 15). Register-only
// serial chains; LDS only off-chain (flush/backtrace/e-prefetch).
__global__ __launch_bounds__(64) void k_rec(const float* __restrict__ e,
        const int* __restrict__ mask,
        const float* __restrict__ trans,
        const float* __restrict__ start,
        const float* __restrict__ endp,
        float* __restrict__ pa, float* __restrict__ pb,
        double* __restrict__ Ca, double* __restrict__ Cb,
        double* __restrict__ zd,
        float* __restrict__ tags_out)
{
    __shared__ __align__(16) char smem[78336];
    int bid = blockIdx.x;
    int tid = threadIdx.x;
    int r8 = tid >> 3, q = tid & 7;

    int rr = tid & 15;            // row position
    int g  = tid >> 4;            // quad-row index 0..3
    int s0h = 16 * (g & 1);       // source-half base
    int jl  = rr + 16 * (g >> 1); // output state of this lane
    int sig0 = s0h + rr;          // own source index (m=0)
    bool lfix = (g == 1) || (g == 2);   // lanes taking the cross32 value

    if (bid < 256) {
        int role = bid >> 7;     // 0=alpha, 1=beta
        int b    = bid & 127;
        float (*ebuf)[4096] = (float(*)[4096])smem;
        float (*pbuf)[4096] = (float(*)[4096])(smem + 32768);
        double (*cbuf)[128] = (double(*)[128])(smem + 65536);

        BALLOTS(ma, b);
        float Eh[16];

        if (role == 0) {
            // ---- alpha: Eh[m] = exp(trans[sigma(m)][jl]), sigma(m)=s0h+((rr-m)&15) ----
            #pragma unroll
            for (int m = 0; m < 16; ++m)
                Eh[m] = __expf(trans[(s0h + ((rr - m) & 15)) * T + jl]);

            STAGEXP(0);
            int j0 = tid & 31;
            float a0 = e[(0 * BATCH + b) * T + j0] + start[j0];
            float m = a0;
            #pragma unroll
            for (int d = 1; d < 32; d <<= 1) m = fmaxf(m, __shfl_xor(m, d));
            float v = __expf(a0 - m);
            float s = v;
            #pragma unroll
            for (int d = 1; d < 32; d <<= 1) s += __shfl_xor(s, d);
            float p0 = v / s;
            double C = (double)m + (double)__logf(s);
            pbuf[0][j0] = p0;
            if (tid == 0) cbuf[0][0] = C;
            float p  = pbuf[0][jl];      // state-wise register (quad-duplicated)
            float pv = pbuf[0][sig0];    // quad-layout source register

            for (int c = 0; c < 4; ++c) {
                int i0 = c ? c * 128 : 1, i1 = c * 128 + 127;
                float enext = ebuf[c & 1][(i0 & 127) * 32 + jl];
                for (int i = i0; i <= i1; ++i) {
                    float ecur = enext;
                    if (i < i1) enext = ebuf[c & 1][((i + 1) & 127) * 32 + jl];
                    float qq;
                    DPPMV(qq, pv, Eh);
                    float vv = qq * ecur;
                    if (MB(ma, i)) p = vv;
                    if ((i & 7) == 0) {
                        float ss; RLSUMQ(ss, p);
                        p = p / ss; C += (double)__logf(ss);
                    }
                    pbuf[c & 1][(i & 127) * 32 + jl] = p;
                    if (tid == 0) cbuf[c & 1][i & 127] = C;
                    float cw = cross32(p);
                    pv = lfix ? cw : p;
                }
                if (c < 3) STAGEXP(c + 1);
                FLUSHPC(pa, Ca, c);
            }
            float t = p * __expf(endp[jl]);
            float sz; RLSUMQ(sz, t);
            if (tid == 0) zd[b] = C + (double)__logf(sz);
        } else {
            // ---- beta: Eh[m] = exp(trans[jl][sigma(m)]) ----
            #pragma unroll
            for (int m = 0; m < 16; ++m)
                Eh[m] = __expf(trans[jl * T + s0h + ((rr - m) & 15)]);

            STAGEXP(3);
            int j0 = tid & 31;
            float v0 = endp[j0];
            float m = v0;
            #pragma unroll
            for (int d = 1; d < 32; d <<= 1) m = fmaxf(m, __shfl_xor(m, d));
            float v = __expf(v0 - m);
            float s = v;
            #pragma unroll
            for (int d = 1; d < 32; d <<= 1) s += __shfl_xor(s, d);
            float p0 = v / s;
            double C = (double)m + (double)__logf(s);
            pbuf[1][127 * 32 + j0] = p0;
            if (tid == 0) cbuf[1][127] = C;
            float p  = pbuf[1][127 * 32 + jl];
            float pv = pbuf[1][127 * 32 + sig0];

            for (int c = 0; c < 4; ++c) {
                int iS = 511 - 128 * c;
                int iE = (c < 3) ? (384 - 128 * c) : 1;
                int bI = (3 - c) & 1;
                float enext = ebuf[bI][(iS & 127) * 32 + sig0];
                for (int i = iS; i >= iE; --i) {
                    float ecur = enext;
                    if (i > iE) enext = ebuf[bI][((i - 1) & 127) * 32 + sig0];
                    float pe = pv * ecur;
                    float qq;
                    DPPMV(qq, pe, Eh);
                    if (MB(ma, i)) p = qq;
                    if ((i & 7) == 0) {
                        float ss; RLSUMQ(ss, p);
                        p = p / ss; C += (double)__logf(ss);
                    }
                    int orow = i - 1, lb = (orow >> 7) & 1;
                    pbuf[lb][(orow & 127) * 32 + jl] = p;
                    if (tid == 0) cbuf[lb][orow & 127] = C;
                    float cw = cross32(p);
                    pv = lfix ? cw : p;
                }
                if (c < 3) STAGEXP(2 - c);
                FLUSHPC(pb, Cb, 3 - c);
            }
        }
    } else {
        // ---- viterbi: quad-layout DPP max-plus forward + ballot backtrace ----
        int b2 = bid - 256;
        float* ebufv = (float*)smem;                       //  8 KB: 64 rows x 32
        float* sbuf  = (float*)(smem + 8192);              // 64 KB: 512 rows x 32
        float* tldsT = (float*)(smem + 73728);             //  4 KB: transposed trans
        unsigned char* tagb = (unsigned char*)(smem + 77824);  // 512 B

        BALLOTS(ma, b2);

        #pragma unroll
        for (int k = 0; k < 16; ++k) {
            int idx = k * 64 + tid;
            int nn = idx >> 5, jj = idx & 31;
            tldsT[jj * 32 + nn] = trans[nn * T + jj];
        }

        float Vh[16];
        #pragma unroll
        for (int m = 0; m < 16; ++m)
            Vh[m] = trans[(s0h + ((rr - m) & 15)) * T + jl];

        STAGEV(0);
        int j0 = tid & 31;
        float sc0 = start[j0] + ebufv[j0];
        sbuf[j0] = sc0;
        float sc = sbuf[jl];
        float sv = sbuf[sig0];

        for (int c = 0; c < 8; ++c) {
            int i0 = c ? c * 64 : 1, i1 = c * 64 + 63;
            float ejnext = ebufv[(i0 & 63) * 32 + jl];
            for (int i = i0; i <= i1; ++i) {
                float ej = ejnext;
                if (i < i1) ejnext = ebufv[((i + 1) & 63) * 32 + jl];
                float mm;
                DPPMAX(mm, sv, Vh);
                float v = mm + ej;
                if (MB(ma, i)) sc = v;
                sbuf[i * 32 + jl] = sc;
                float cw = cross32(sc);
                sv = lfix ? cw : sc;
            }
            if (c < 7) STAGEV(c + 1);
        }

        // final argmax over states (duplicated across lanes; first index on ties)
        float fs = sc + endp[jl];
        int fj = jl;
        #pragma unroll
        for (int d = 1; d < 64; d <<= 1) {
            float ov = __shfl_xor(fs, d); int oj = __shfl_xor(fj, d);
            if (ov > fs || (ov == fs && oj < fj)) { fs = ov; fj = oj; }
        }
        int jstar = __builtin_amdgcn_readfirstlane(fj);
        tagb[SEQ - 1] = (unsigned char)jstar;

        // backtrace: ballot equality on exact reference candidates (verified r13-16)
        int n = tid & 31;
        for (int c = 7; c >= 0; --c) {
            if (c < 7) STAGEV(c);
            int iS = c * 64 + 63, iE = c ? c * 64 : 1;
            for (int i = iS; i >= iE; --i) {
                float sn = sbuf[(i - 1) * 32 + n];
                float tn = tldsT[jstar * 32 + n];
                float en = ebufv[(i & 63) * 32 + jstar];
                float cn = (sn + tn) + en;
                float v;
                if (MB(ma, i)) {
                    v = sbuf[i * 32 + jstar];
                } else {
                    v = cn;
                    #pragma unroll
                    for (int d = 1; d < 32; d <<= 1)
                        v = fmaxf(v, __shfl_xor(v, d));
                }
                unsigned long long bm = __ballot(cn == v);
                jstar = (int)__builtin_ctzll(bm);
                tagb[i - 1] = (unsigned char)jstar;
            }
        }
        #pragma unroll
        for (int k2 = 0; k2 < 8; ++k2) {
            int idx = k2 * 64 + tid;
            tags_out[(size_t)idx * BATCH + b2] = (float)tagb[idx];
        }
    }
}

// ---------------- probs = pa * pb * exp(Ca + Cb - z)  (float math; double only for the sum) ----------------
__global__ __launch_bounds__(256) void k_probs(const float* __restrict__ pa,
        const float* __restrict__ pb, const double* __restrict__ Ca,
        const double* __restrict__ Cb, const double* __restrict__ zd,
        float* __restrict__ out)
{
    int idx = blockIdx.x * 256 + threadIdx.x;
    int ib = idx >> 3;
    int b = ib & (BATCH - 1);
    double ex = Ca[ib] + Cb[ib] - zd[b];
    float scl = __expf((float)ex);
    float4 a = ((const float4*)pa)[idx];
    float4 c = ((const float4*)pb)[idx];
    float4 o;
    o.x = a.x * c.x * scl;
    o.y = a.y * c.y * scl;
    o.z = a.z * c.z * scl;
    o.w = a.w * c.w * scl;
    ((float4*)out)[idx] = o;
}

extern "C" void kernel_launch(void* const* d_in, const int* in_sizes, int n_in,
                              void* d_out, int out_size, void* d_ws, size_t ws_size,
                              hipStream_t stream) {
    const float* features = (const float*)d_in[0];
    const int*   mask     = (const int*)d_in[1];
    const float* W        = (const float*)d_in[2];
    const float* bias     = (const float*)d_in[3];
    const float* trans    = (const float*)d_in[4];
    const float* startp   = (const float*)d_in[5];
    const float* endp     = (const float*)d_in[6];

    char* ws = (char*)d_ws;
    double* Ca = (double*)(ws + 0);
    double* Cb = (double*)(ws + 524288);
    double* zd = (double*)(ws + 1048576);
    float*  Wt = (float*)(ws + 1049600);
    float*  e  = (float*)(ws + 1180672);
    float*  pa = (float*)(ws + 9569280);
    float*  pb = (float*)(ws + 17957888);

    float* probs_out = (float*)d_out;
    float* tags_out  = probs_out + (size_t)SEQ * BATCH * T;

    k_wt<<<128, 256, 0, stream>>>(W, Wt);
    k_emis<<<1024, 256, 0, stream>>>(features, Wt, bias, e);
    k_rec<<<384, 64, 0, stream>>>(e, mask, trans, startp, endp,
                                  pa, pb, Ca, Cb, zd, tags_out);
    k_probs<<<2048, 256, 0, stream>>>(pa, pb, Ca, Cb, zd, probs_out);
}